// Round 1
// baseline (70.898 us; speedup 1.0000x reference)
//
#include <hip/hip_runtime.h>

// Problem constants (from reference): N1=2048 coarse voxels, N2=32768 fine
// voxels, F=64 features, SPATIAL=512, i=3 -> scale=8, coarse_size=64.
#define N1 2048
#define N2 32768
#define F  64
#define SPATIAL 512
#define EMPTY 0x7fffffff

// --- Kernel 1: init dense coarse grid to EMPTY (ws is re-poisoned to 0xAA
// before every timed launch, so this must run every call). ---
__global__ void efm_init_grid(int* __restrict__ grid, int n) {
    int idx = blockIdx.x * blockDim.x + threadIdx.x;
    if (idx < n) grid[idx] = EMPTY;
}

// --- Kernel 2: scatter coarse voxel indices; atomicMin == first-True argmax
// semantics for duplicate cells. ---
__global__ void efm_populate(const float* __restrict__ fm,
                             const int* __restrict__ ip,
                             int* __restrict__ grid) {
    int n1 = blockIdx.x * blockDim.x + threadIdx.x;
    if (n1 >= N1) return;
    int i  = ip[0];
    int cs = SPATIAL >> i;               // coarse_size = 64 for i=3
    float4 f = ((const float4*)fm)[n1];  // integer-valued fp32 coords
    int x = (int)f.x, y = (int)f.y, z = (int)f.z;
    atomicMin(&grid[(x * cs + y) * cs + z], n1);
}

// --- Kernel 3: one wave (64 lanes) per fine voxel. All lanes compute sel
// (3 broadcast loads from L1), lane l gathers feature l (coalesced 256B
// read & write per wave), lanes 0-3 write the 4 coords. ---
__global__ void efm_gather(const float* __restrict__ fm,
                           const float* __restrict__ xf,
                           const float* __restrict__ co,
                           const int*   __restrict__ ip,
                           const int*   __restrict__ grid,
                           float* __restrict__ out_coords,
                           float* __restrict__ out_feats) {
    int tid  = blockIdx.x * blockDim.x + threadIdx.x;
    int n2   = tid >> 6;
    int lane = tid & 63;
    if (n2 >= N2) return;
    int i  = ip[0];
    int cs = SPATIAL >> i;
    float4 c = ((const float4*)co)[n2];
    // cell = floor(c / 2^i) per dim; c is an exact small integer in fp32.
    int cx = ((int)c.x) >> i;
    int cy = ((int)c.y) >> i;
    int cz = ((int)c.z) >> i;
    int sel = grid[(cx * cs + cy) * cs + cz];
    if (sel == EMPTY) sel = 0;           // argmax of all-False column -> 0
    out_feats[n2 * F + lane] = xf[sel * F + lane];
    if (lane < 4) out_coords[n2 * 4 + lane] = fm[sel * 4 + lane];
}

// --- Fallback (only if ws too small for the 1 MB grid): wave-scan brute
// force, ballot picks the first matching coarse index. ---
__global__ void efm_brute(const float* __restrict__ fm,
                          const float* __restrict__ xf,
                          const float* __restrict__ co,
                          const int*   __restrict__ ip,
                          float* __restrict__ out_coords,
                          float* __restrict__ out_feats) {
    int tid  = blockIdx.x * blockDim.x + threadIdx.x;
    int n2   = tid >> 6;
    int lane = tid & 63;
    if (n2 >= N2) return;
    float scale = (float)(1 << ip[0]);
    float4 c = ((const float4*)co)[n2];
    int sel = 0;
    for (int base = 0; base < N1; base += 64) {
        float4 f = ((const float4*)fm)[base + lane];
        bool m = (f.x * scale <= c.x) && (f.x * scale + scale > c.x)
              && (f.y * scale <= c.y) && (f.y * scale + scale > c.y)
              && (f.z * scale <= c.z) && (f.z * scale + scale > c.z)
              && (f.w * scale <= c.w) && (f.w * scale + scale > c.w);
        unsigned long long b = __ballot(m);
        if (b) { sel = base + __ffsll((unsigned long long)b) - 1; break; }
    }
    out_feats[n2 * F + lane] = xf[sel * F + lane];
    if (lane < 4) out_coords[n2 * 4 + lane] = fm[sel * 4 + lane];
}

extern "C" void kernel_launch(void* const* d_in, const int* in_sizes, int n_in,
                              void* d_out, int out_size, void* d_ws, size_t ws_size,
                              hipStream_t stream) {
    const float* fm = (const float*)d_in[0];   // feature_map (N1,4) fp32
    const float* xf = (const float*)d_in[1];   // x_features  (N1,F) fp32
    const float* co = (const float*)d_in[2];   // coords      (N2,4) fp32
    const int*   ip = (const int*)d_in[3];     // i (scalar int32)

    float* out_coords = (float*)d_out;             // (N2,4)  flat first
    float* out_feats  = (float*)d_out + N2 * 4;    // (N2,F)  flat second

    const size_t grid_cells = 64 * 64 * 64;        // coarse_size^3 for i=3
    if (ws_size >= grid_cells * sizeof(int)) {
        int* grid = (int*)d_ws;
        efm_init_grid<<<(int)((grid_cells + 255) / 256), 256, 0, stream>>>(
            grid, (int)grid_cells);
        efm_populate<<<(N1 + 255) / 256, 256, 0, stream>>>(fm, ip, grid);
        efm_gather<<<(N2 * 64 + 255) / 256, 256, 0, stream>>>(
            fm, xf, co, ip, grid, out_coords, out_feats);
    } else {
        efm_brute<<<(N2 * 64 + 255) / 256, 256, 0, stream>>>(
            fm, xf, co, ip, out_coords, out_feats);
    }
}